// Round 1
// baseline (2142.808 us; speedup 1.0000x reference)
//
#include <hip/hip_runtime.h>
#include <cstddef>

// Problem constants
#define B_   4
#define NS_  96
#define T_   8
#define H_   256
#define N_   97      // NS + 1
#define NL_  6       // NUM_LAYERS
#define R_   388     // B_ * N_
#define MEGA_GRID 256

// fast gates: v_exp_f32 (2^x) + v_rcp_f32
__device__ __forceinline__ float sigm(float x) {
    return __builtin_amdgcn_rcpf(1.0f + __builtin_amdgcn_exp2f(-1.44269504f * x));
}
__device__ __forceinline__ float tanh_f(float x) {
    return 1.0f - 2.0f * __builtin_amdgcn_rcpf(1.0f + __builtin_amdgcn_exp2f(2.88539008f * x));
}

__device__ __forceinline__ void fma16(float4 a, float4 w0, float4 w1, float4 w2,
                                      float4 w3, float* acc) {
    acc[0] = fmaf(a.x, w0.x, acc[0]); acc[1] = fmaf(a.x, w0.y, acc[1]);
    acc[2] = fmaf(a.x, w0.z, acc[2]); acc[3] = fmaf(a.x, w0.w, acc[3]);
    acc[0] = fmaf(a.y, w1.x, acc[0]); acc[1] = fmaf(a.y, w1.y, acc[1]);
    acc[2] = fmaf(a.y, w1.z, acc[2]); acc[3] = fmaf(a.y, w1.w, acc[3]);
    acc[0] = fmaf(a.z, w2.x, acc[0]); acc[1] = fmaf(a.z, w2.y, acc[1]);
    acc[2] = fmaf(a.z, w2.z, acc[2]); acc[3] = fmaf(a.z, w2.w, acc[3]);
    acc[0] = fmaf(a.w, w3.x, acc[0]); acc[1] = fmaf(a.w, w3.y, acc[1]);
    acc[2] = fmaf(a.w, w3.z, acc[2]); acc[3] = fmaf(a.w, w3.w, acc[3]);
}

// ============ prologue: 512-thr blocks ============
// bid<384: xz 64x128 tiles; 384-385: cz; 386-387: hw; 388: ck + ctr zero; 389..437: init.
__global__ __launch_bounds__(512) void prologue(
        const int* __restrict__ ids, const float* __restrict__ embed,
        const float* __restrict__ Wx_s, const float* __restrict__ b_s,
        const float* __restrict__ b_se, const float* __restrict__ Wx_e,
        const float* __restrict__ b_e, const float* __restrict__ W_sd,
        const float* __restrict__ b_sd, const float* __restrict__ Wh_e,
        const float* __restrict__ init_a, const float* __restrict__ init_b,
        float* __restrict__ xz, float* __restrict__ cz, float* __restrict__ ck,
        float* __restrict__ hw, float* __restrict__ c0, float* __restrict__ h0,
        float* __restrict__ p0, int* __restrict__ ctr) {
    int bid = blockIdx.x, t = threadIdx.x;
    if (bid < 384) {                      // xz = embed[ids] @ Wx_s + b_s, 64x128 tile
        __shared__ float As[64][260];
        __shared__ int ridx[64];
        int r0 = (bid >> 3) * 64, n0 = (bid & 7) * 128;
        if (t < 64) ridx[t] = ids[r0 + t];
        __syncthreads();
#pragma unroll
        for (int m = 0; m < 8; m++) {     // stage 64x256 (8 float4/thread)
            int L = m * 512 + t;
            int r = L >> 6, c4 = (L & 63) * 4;
            *(float4*)&As[r][c4] = *(const float4*)(embed + (size_t)ridx[r] * 256 + c4);
        }
        __syncthreads();
        int rg = t >> 5, cg = t & 31;     // 16 row-groups x 32 col-quads
        float acc[4][4] = {};
        const float* wp = Wx_s + n0 + 4 * cg;
#pragma unroll 4
        for (int kb = 0; kb < 64; kb++) {
            float4 w0 = *(const float4*)(wp + (size_t)(4 * kb + 0) * 1024);
            float4 w1 = *(const float4*)(wp + (size_t)(4 * kb + 1) * 1024);
            float4 w2 = *(const float4*)(wp + (size_t)(4 * kb + 2) * 1024);
            float4 w3 = *(const float4*)(wp + (size_t)(4 * kb + 3) * 1024);
#pragma unroll
            for (int i = 0; i < 4; i++) {
                float4 a = *(const float4*)&As[rg * 4 + i][4 * kb];
                fma16(a, w0, w1, w2, w3, acc[i]);
            }
        }
        int col = n0 + 4 * cg;
        float4 bv = *(const float4*)&b_s[col];
#pragma unroll
        for (int i = 0; i < 4; i++) {
            int r = r0 + rg * 4 + i;
            float4 o = make_float4(acc[i][0] + bv.x, acc[i][1] + bv.y,
                                   acc[i][2] + bv.z, acc[i][3] + bv.w);
            *(float4*)&xz[(size_t)r * 1024 + col] = o;
        }
    } else if (bid < 386) {               // cz[n] = b_e + b_se@Wx_e
        int n = (bid - 384) * 512 + t;
        float acc = b_e[n];
        for (int k = 0; k < 256; k++) acc = fmaf(b_se[k], Wx_e[(size_t)k * 1024 + n], acc);
        cz[n] = acc;
    } else if (bid < 388) {               // hw[n] = cz[n] + init_b@Wh_e
        int n = (bid - 386) * 512 + t;
        float acc = b_e[n];
        for (int k = 0; k < 256; k++) {
            acc = fmaf(b_se[k], Wx_e[(size_t)k * 1024 + n], acc);
            acc = fmaf(init_b[k], Wh_e[(size_t)k * 1024 + n], acc);
        }
        hw[n] = acc;
    } else if (bid == 388) {              // ck + barrier-counter zeroing
        if (t < 256) {
            float acc = b_sd[t];
            for (int k = 0; k < 256; k++) acc = fmaf(b_se[k], W_sd[(size_t)k * 256 + t], acc);
            ck[t] = acc;
        } else if (t < 272) {
            ctr[t - 256] = 0;             // 12 lstm group ctrs + 1 mega ctr + pad
        }
    } else {                              // init c0/h0/p0: 8 rows per block
        int r0 = (bid - 389) * 8 + (t >> 8) * 4;
        int col = t & 255;
        float ia = init_a[col], ib = init_b[col];
#pragma unroll
        for (int rr = 0; rr < 4; rr++) {
            int row = r0 + rr;
            if (row < R_) {
                c0[(size_t)row * 256 + col] = ia;
                h0[(size_t)row * 256 + col] = ib;
                if (col == 0) p0[row] = ((row % N_) == 0) ? 1.0f : 0.0f;
            }
        }
    }
}

// ============ fused LSTM: all 8 steps in one persistent kernel ============
// grid (16 ct, 12 st), 256 thr, 1 block/CU (106KB LDS), 192 blocks co-resident.
// Wh staged ONCE; cell state in 2 registers; h exchanged via per-st group barriers.
__global__ __launch_bounds__(256) void lstm_fused(const float* __restrict__ xz,
        const float* __restrict__ Wh, float* __restrict__ hbuf, int* __restrict__ ctr) {
    __shared__ float Wh_s[256][64];
    __shared__ float h_s[32][260];
    __shared__ float zs[32][68];
    int t = threadIdx.x;
    int ct = blockIdx.x, st = blockIdx.y;
    int et0 = ct * 16, s0 = st * 32;
    // stage Wh slice once for all 8 steps
#pragma unroll
    for (int m = 0; m < 16; m++) {
        int L = m * 256 + t;
        int k = L >> 4, f = L & 15;
        int gg = f >> 2, qq = f & 3;
        *(float4*)&Wh_s[k][f * 4] = *(const float4*)&Wh[(size_t)k * 1024 + gg * 256 + et0 + qq * 4];
    }
    // ---- step 0: h0 computed locally for all 32 stmts, all 256 cols ----
    for (int seq = 0; seq < 32; seq++) {
        const float* z0 = xz + ((size_t)(s0 + seq) * T_) * 1024;
        float gi = z0[t], gg = z0[512 + t], go = z0[768 + t];
        float c0v = sigm(gi) * tanh_f(gg);
        h_s[seq][t] = sigm(go) * tanh_f(c0v);
    }
    float creg[2];
    {
        int sqA = t >> 4, e = et0 + (t & 15);
#pragma unroll
        for (int u = 0; u < 2; u++) {
            const float* z0 = xz + ((size_t)(s0 + sqA + u * 16) * T_) * 1024;
            creg[u] = sigm(z0[e]) * tanh_f(z0[512 + e]);
        }
    }
    __syncthreads();
    int sp = t >> 4, cq = t & 15;
    int g = cq >> 2, q4 = cq & 3;
    int gcol = g * 256 + et0 + q4 * 4;
    int seqA = t >> 4, e = t & 15;
    int epoch = 0;
    for (int step = 1; step < T_; step++) {
        if (step >= 2) {                  // re-stage h (written by all 16 ct-blocks)
#pragma unroll
            for (int m = 0; m < 8; m++) {
                int L = m * 256 + t;
                int seq = L >> 6, c4 = (L & 63) * 4;
                *(float4*)&h_s[seq][c4] = *(const float4*)&hbuf[(size_t)(s0 + seq) * H_ + c4];
            }
            __syncthreads();
        }
        float4 a0 = *(const float4*)(xz + ((size_t)(s0 + sp) * T_ + step) * 1024 + gcol);
        float4 a1 = *(const float4*)(xz + ((size_t)(s0 + sp + 16) * T_ + step) * 1024 + gcol);
#pragma unroll 4
        for (int k = 0; k < 256; k++) {
            float4 w4 = *(const float4*)&Wh_s[k][cq * 4];
            float hA = h_s[sp][k];
            float hB = h_s[sp + 16][k];
            a0.x = fmaf(hA, w4.x, a0.x); a0.y = fmaf(hA, w4.y, a0.y);
            a0.z = fmaf(hA, w4.z, a0.z); a0.w = fmaf(hA, w4.w, a0.w);
            a1.x = fmaf(hB, w4.x, a1.x); a1.y = fmaf(hB, w4.y, a1.y);
            a1.z = fmaf(hB, w4.z, a1.z); a1.w = fmaf(hB, w4.w, a1.w);
        }
        *(float4*)&zs[sp][cq * 4] = a0;
        *(float4*)&zs[sp + 16][cq * 4] = a1;
        __syncthreads();
#pragma unroll
        for (int u = 0; u < 2; u++) {
            int seq = seqA + u * 16;
            float gi = zs[seq][e], gf = zs[seq][16 + e], gg = zs[seq][32 + e], go = zs[seq][48 + e];
            float cn = sigm(gf) * creg[u] + sigm(gi) * tanh_f(gg);
            creg[u] = cn;
            hbuf[(size_t)(s0 + seq) * H_ + et0 + e] = sigm(go) * tanh_f(cn);
        }
        if (step < T_ - 1) {              // group barrier: 16 ct-blocks of this st
            __threadfence();
            __syncthreads();
            epoch++;
            if (t == 0) {
                atomicAdd(&ctr[st], 1);
                while (__hip_atomic_load(&ctr[st], __ATOMIC_ACQUIRE,
                                         __HIP_MEMORY_SCOPE_AGENT) < 16 * epoch)
                    __builtin_amdgcn_s_sleep(1);
            }
            __syncthreads();
            __threadfence();
        }
    }
}

// ============ mega: cumsum + s + q/r + softmax + 6 layers, one persistent kernel ============
__device__ __forceinline__ void stage_16rows(float (*As)[260], const float* src,
                                             int r0, int t) {
#pragma unroll
    for (int m = 0; m < 2; m++) {
        int L = m * 512 + t;
        int r = L >> 6, c4 = (L & 63) * 4;
        int rr = r0 + r;
        float4 v = make_float4(0.f, 0.f, 0.f, 0.f);
        if (rr < R_) v = *(const float4*)(src + (size_t)rr * 256 + c4);
        *(float4*)&As[r][c4] = v;
    }
}

__device__ __forceinline__ void tile_gemm(const float (*As)[260], const float* wp,
                                          int NC, int rg, float acc[2][4]) {
#pragma unroll 2
    for (int kb = 0; kb < 64; kb++) {
        float4 w0 = *(const float4*)(wp + (size_t)(4 * kb + 0) * NC);
        float4 w1 = *(const float4*)(wp + (size_t)(4 * kb + 1) * NC);
        float4 w2 = *(const float4*)(wp + (size_t)(4 * kb + 2) * NC);
        float4 w3 = *(const float4*)(wp + (size_t)(4 * kb + 3) * NC);
#pragma unroll
        for (int i = 0; i < 2; i++) {
            float4 a = *(const float4*)&As[rg * 2 + i][4 * kb];
            fma16(a, w0, w1, w2, w3, acc[i]);
        }
    }
}

__global__ __launch_bounds__(512, 4) void mega(
        const float* __restrict__ stmt, const float* __restrict__ W_se,
        const float* __restrict__ Wx_e, const float* __restrict__ W_sd,
        const float* __restrict__ Wh_e, const float* __restrict__ hw,
        const float* __restrict__ cz, const float* __restrict__ ck,
        const float* __restrict__ Wd1, const int* __restrict__ code_length,
        float* __restrict__ pref, float* __restrict__ s_, float* __restrict__ q,
        float* __restrict__ ve, float* __restrict__ r_, float* __restrict__ rT,
        float* __restrict__ spT_mid, float* __restrict__ spT0, float* __restrict__ spT5,
        float* __restrict__ c0, float* __restrict__ c1, float* __restrict__ h0,
        float* __restrict__ h1, float* __restrict__ p0, float* __restrict__ p1,
        float* __restrict__ out, int* __restrict__ ctr) {
    __shared__ __align__(16) char smemraw[16896];
    int bid = blockIdx.x, t = threadIdx.x;
    int bar_epoch = 0;
    auto gbar = [&]() {
        __threadfence();
        __syncthreads();
        ++bar_epoch;
        if (t == 0) {
            atomicAdd(ctr, 1);
            while (__hip_atomic_load(ctr, __ATOMIC_ACQUIRE,
                                     __HIP_MEMORY_SCOPE_AGENT) < MEGA_GRID * bar_epoch)
                __builtin_amdgcn_s_sleep(2);
        }
        __syncthreads();
        __threadfence();
    };

    // ---- phase 1: cumsum -> pref ----
    if (bid < B_ && t < 256) {
        int b = bid;
        float run = 0.0f;
        pref[((size_t)b * N_) * H_ + t] = 0.0f;
        const float* sp = stmt + (size_t)b * NS_ * H_ + t;
        for (int n = 1; n < N_; n++) {
            run += sp[(size_t)(n - 1) * H_];
            pref[((size_t)b * N_ + n) * H_ + t] = run;
        }
    }
    gbar();

    // ---- phase 2: s_ = pref @ W_se (25 tiles of 16x256) ----
    {
        float (*As)[260] = reinterpret_cast<float(*)[260]>(smemraw);
        if (bid < 25) {
            int r0 = bid * 16;
            stage_16rows(As, pref, r0, t);
            __syncthreads();
            int rg = t >> 6, cg = t & 63;
            float acc[2][4] = {};
            tile_gemm(As, W_se + 4 * cg, 256, rg, acc);
            int col = 4 * cg;
#pragma unroll
            for (int i = 0; i < 2; i++) {
                int r = r0 + rg * 2 + i;
                if (r < R_) {
                    float4 o = make_float4(acc[i][0], acc[i][1], acc[i][2], acc[i][3]);
                    *(float4*)&s_[(size_t)r * 256 + col] = o;
                }
            }
        }
    }
    gbar();

    // ---- phase 3: q = s_@Wx_e (+ ve0 = hw - q); r = s_@W_sd (+ rT) ----
    {
        float (*As)[260] = reinterpret_cast<float(*)[260]>(smemraw);
        if (bid < 125) {
            int rt = bid % 25, sel = bid / 25;   // sel 0..3: q col-tiles; 4: r tile
            int r0 = rt * 16;
            stage_16rows(As, s_, r0, t);
            __syncthreads();
            int rg = t >> 6, cg = t & 63;
            float acc[2][4] = {};
            bool isq = sel < 4;
            const float* W = isq ? Wx_e : W_sd;
            int NC = isq ? 1024 : 256;
            int n0 = isq ? sel * 256 : 0;
            tile_gemm(As, W + n0 + 4 * cg, NC, rg, acc);
            int col = n0 + 4 * cg;
#pragma unroll
            for (int i = 0; i < 2; i++) {
                int r = r0 + rg * 2 + i;
                if (r < R_) {
                    float4 o = make_float4(acc[i][0], acc[i][1], acc[i][2], acc[i][3]);
                    if (isq) {
                        *(float4*)&q[(size_t)r * 1024 + col] = o;
                        float4 hwv = *(const float4*)&hw[col];
                        float4 v0 = make_float4(hwv.x - o.x, hwv.y - o.y,
                                                hwv.z - o.z, hwv.w - o.w);
                        *(float4*)&ve[(size_t)r * 1024 + col] = v0;
                    } else {
                        *(float4*)&r_[(size_t)r * 256 + col] = o;
                        int b = r / N_, n = r - b * N_;
                        rT[((size_t)b * 256 + col + 0) * 128 + n] = o.x;
                        rT[((size_t)b * 256 + col + 1) * 128 + n] = o.y;
                        rT[((size_t)b * 256 + col + 2) * 128 + n] = o.z;
                        rT[((size_t)b * 256 + col + 3) * 128 + n] = o.w;
                    }
                }
            }
        }
    }
    gbar();

    // ---- phase 4: logits + masked softmax (layer-invariant) ----
    {
        float* ri  = reinterpret_cast<float*>(smemraw);          // 256
        float* ckl = ri + 256;                                   // 256
        float* wd  = ckl + 256;                                  // 256
        float (*part)[128] = reinterpret_cast<float(*)[128]>(wd + 256);  // 4x128
        float* red = reinterpret_cast<float*>(part + 4);         // 128
#pragma unroll 1
        for (int bi = bid; bi < R_; bi += MEGA_GRID) {
            int b = bi / N_, i = bi - b * N_;
            if (t < 256) {
                ri[t]  = r_[(size_t)bi * 256 + t];
                ckl[t] = ck[t];
                wd[t]  = Wd1[256 + t];
            }
            __syncthreads();
            int j = t & 127, half = t >> 7;    // 4 h-slices of 64
            int len = code_length[b] / T_;
            bool valid = (j < N_) && ((j > i && j <= len) || (j == len));
            float acc = 0.0f;
            if (valid) {
                const float* rTb = rT + (size_t)b * 256 * 128 + j;
                int hbase = half * 64;
#pragma unroll 4
                for (int hh = 0; hh < 64; hh++) {
                    int h = hbase + hh;
                    float v = rTb[(size_t)h * 128] - ri[h] + ckl[h];
                    acc = fmaf(fmaxf(v, 0.0f), wd[h], acc);
                }
            }
            part[half][j] = acc;
            __syncthreads();
            float logit = -3.0e38f;
            if (t < 128) {
                if (valid) logit = part[0][j] + part[1][j] + part[2][j] + part[3][j];
                red[j] = logit;
            }
            __syncthreads();
            for (int off = 64; off; off >>= 1) {
                if (t < off) red[t] = fmaxf(red[t], red[t + off]);
                __syncthreads();
            }
            float m = red[0];
            __syncthreads();
            float ee = (t < 128 && valid)
                           ? __builtin_amdgcn_exp2f(1.44269504f * (logit - m)) : 0.0f;
            if (t < 128) red[j] = ee;
            __syncthreads();
            for (int off = 64; off; off >>= 1) {
                if (t < off) red[t] += red[t + off];
                __syncthreads();
            }
            float ssum = red[0];
            if (t < 128 && j < N_) {
                size_t o = ((size_t)b * N_ + j) * 128 + i;
                spT_mid[o] = ee / ssum;
                spT0[o] = (j == 1) ? 1.0f : 0.0f;
                spT5[o] = (j == len) ? 1.0f : 0.0f;
            }
        }
    }
    gbar();

    // ---- phase 5: execution layers (aggregate + ve-gemm, all in-kernel) ----
    {
        float* qj    = reinterpret_cast<float*>(smemraw);        // 1024
        float* wcol  = qj + 1024;                                // 128
        float* redA  = wcol + 128;                               // 128
        int*   vlist = reinterpret_cast<int*>(redA + 128);       // 128
        int*   nv_s  = vlist + 128;                              // 1 (+pad)
        float* parts = reinterpret_cast<float*>(nv_s + 4);       // [2][2][256]
        float (*As)[260] = reinterpret_cast<float(*)[260]>(smemraw);
        int* anyflag = reinterpret_cast<int*>(smemraw + 16640);
#pragma unroll 1
        for (int layer = 0; layer < NL_; layer++) {
            const float* pc = (layer & 1) ? p1 : p0;
            float*       pn = (layer & 1) ? p0 : p1;
            const float* cc = (layer & 1) ? c1 : c0;
            float*       cn = (layer & 1) ? c0 : c1;
            const float* hc = (layer & 1) ? h1 : h0;
            float*       hn = (layer & 1) ? h0 : h1;
            if (layer == NL_ - 1) hn = out;
            const float* spT = (layer == 0) ? spT0
                             : (layer == NL_ - 1) ? spT5 : spT_mid;
            // ---------- aggregate ----------
#pragma unroll 1
            for (int bj = bid; bj < R_; bj += MEGA_GRID) {
                __syncthreads();          // protect smem reuse across iterations
                int b2 = bj / N_, j2 = bj - b2 * N_;
                if (t < 128) {
                    float wv = (t < N_) ? spT[(size_t)bj * 128 + t] * pc[b2 * N_ + t] : 0.f;
                    wcol[t] = wv;
                    redA[t] = wv;
                }
                __syncthreads();
                if (t == 0) {
                    int nv = 0;
                    for (int i2 = 0; i2 < N_; i2++)
                        if (wcol[i2] != 0.0f) vlist[nv++] = i2;
                    *nv_s = nv;
                }
                __syncthreads();
                for (int off = 64; off; off >>= 1) {
                    if (t < off) redA[t] += redA[t + off];
                    __syncthreads();
                }
                float wsum = redA[0];
                if (wsum == 0.0f) {
                    if (t < 256) {
                        cn[(size_t)bj * H_ + t] = 0.0f;
                        hn[(size_t)bj * H_ + t] = 0.0f;
                        if (t == 0) pn[bj] = 0.0f;
                    }
                } else {
                    qj[t] = q[(size_t)bj * 1024 + t];
                    qj[512 + t] = q[(size_t)bj * 1024 + 512 + t];
                    __syncthreads();
                    int hh = t & 255, vs = t >> 8;
                    int nv = *nv_s;
                    float ac = 0.f, ah = 0.f;
                    for (int v = vs; v < nv; v += 2) {
                        int i2 = vlist[v];
                        float wv = wcol[i2];
                        size_t rowi = (size_t)b2 * N_ + i2;
                        if (j2 > i2) {
                            const float* vei = ve + rowi * 1024;
                            float gi = qj[hh] + vei[hh];
                            float gf = qj[256 + hh] + vei[256 + hh];
                            float gg = qj[512 + hh] + vei[512 + hh];
                            float go = qj[768 + hh] + vei[768 + hh];
                            float c2 = cc[rowi * H_ + hh];
                            float cp = sigm(gf) * c2 + sigm(gi) * tanh_f(gg);
                            float hp = sigm(go) * tanh_f(cp);
                            ac = fmaf(wv, cp, ac);
                            ah = fmaf(wv, hp, ah);
                        } else {
                            ac = fmaf(wv, cc[rowi * H_ + hh], ac);
                            ah = fmaf(wv, hc[rowi * H_ + hh], ah);
                        }
                    }
                    parts[(vs * 2 + 0) * 256 + hh] = ac;
                    parts[(vs * 2 + 1) * 256 + hh] = ah;
                    __syncthreads();
                    if (t < 256) {
                        float inv = __builtin_amdgcn_rcpf(wsum + 1e-7f);
                        cn[(size_t)bj * H_ + t] = (parts[0 * 256 + t] + parts[2 * 256 + t]) * inv;
                        hn[(size_t)bj * H_ + t] = (parts[1 * 256 + t] + parts[3 * 256 + t]) * inv;
                        if (t == 0) pn[bj] = wsum;
                    }
                }
            }
            if (layer < NL_ - 1) {
                gbar();
                // ---------- ve = hn @ Wh_e + cz - q, gated by pn ----------
                if (bid < 100) {
                    int rt = bid % 25, ct4 = bid / 25;
                    int r0 = rt * 16, c0c = ct4 * 256;
                    if (t == 0) *anyflag = 0;
                    __syncthreads();
                    if (t < 16 && r0 + t < R_ && pn[r0 + t] != 0.0f) *anyflag = 1;
                    __syncthreads();
                    if (*anyflag) {
                        stage_16rows(As, hn, r0, t);
                        __syncthreads();
                        int rg = t >> 6, cg = t & 63;
                        float acc[2][4] = {};
                        tile_gemm(As, Wh_e + c0c + 4 * cg, 1024, rg, acc);
                        int col = c0c + 4 * cg;
                        float4 czv = *(const float4*)&cz[col];
#pragma unroll
                        for (int i = 0; i < 2; i++) {
                            int r = r0 + rg * 2 + i;
                            if (r < R_) {
                                float4 qv = *(const float4*)(q + (size_t)r * 1024 + col);
                                float4 o = make_float4(acc[i][0] + czv.x - qv.x,
                                                       acc[i][1] + czv.y - qv.y,
                                                       acc[i][2] + czv.z - qv.z,
                                                       acc[i][3] + czv.w - qv.w);
                                *(float4*)&ve[(size_t)r * 1024 + col] = o;
                            }
                        }
                    }
                }
                gbar();
            }
        }
    }
}

// ---------------- host launcher ----------------

extern "C" void kernel_launch(void* const* d_in, const int* in_sizes, int n_in,
                              void* d_out, int out_size, void* d_ws, size_t ws_size,
                              hipStream_t stream) {
    const int*   code_statements = (const int*)d_in[0];
    const int*   code_length = (const int*)d_in[1];
    const float* embed = (const float*)d_in[2];
    const float* Wx_s = (const float*)d_in[3];
    const float* Wh_s = (const float*)d_in[4];
    const float* b_s  = (const float*)d_in[5];
    const float* W_se = (const float*)d_in[6];
    const float* b_se = (const float*)d_in[7];
    const float* Wx_e = (const float*)d_in[8];
    const float* Wh_e = (const float*)d_in[9];
    const float* b_e  = (const float*)d_in[10];
    const float* W_sd = (const float*)d_in[13];
    const float* b_sd = (const float*)d_in[14];
    const float* W_d1 = (const float*)d_in[15];
    // d_in[11] W_hk, d_in[12] b_hk, d_in[16] b_d1: softmax-invariant -> unused
    const float* init_a = (const float*)d_in[17];
    const float* init_b = (const float*)d_in[18];
    float* out = (float*)d_out;

    float* wsf = (float*)d_ws;
    size_t off = 0;
    auto alloc = [&](size_t n) { float* p = wsf + off; off += n; return p; };
    float* cz = alloc(1024);
    float* ck = alloc(256);
    float* hw = alloc(1024);             // init_b@Wh_e + cz
    float* xz = alloc((size_t)3072 * 1024);
    float* stmt = alloc(384 * 256);      // LSTM h buffer
    float* pref = alloc(R_ * 256);
    float* s_   = alloc(R_ * 256);       // pref @ W_se
    float* q  = alloc(R_ * 1024);
    float* r_ = alloc(R_ * 256);
    float* rT = alloc(4 * 256 * 128);
    float* ve = alloc(R_ * 1024);        // h@Wh_e + cz - q
    float* spT_mid = alloc(R_ * 128);
    float* spT0    = alloc(R_ * 128);
    float* spT5    = alloc(R_ * 128);
    float* p0 = alloc(R_);
    float* p1 = alloc(R_);
    float* c0 = alloc(R_ * 256);
    float* c1 = alloc(R_ * 256);
    float* h0 = alloc(R_ * 256);
    float* h1 = alloc(R_ * 256);
    int*   ctr = (int*)alloc(16);        // [0..11] lstm st-group ctrs, [12] mega ctr

    // 1) prologue: xz tiles + cz/ck/hw + state init + ctr zeroing
    prologue<<<dim3(438), 512, 0, stream>>>(code_statements, embed, Wx_s, b_s,
                                            b_se, Wx_e, b_e, W_sd, b_sd, Wh_e,
                                            init_a, init_b, xz, cz, ck, hw, c0, h0, p0,
                                            ctr);
    // 2) all 8 LSTM steps, one persistent kernel (group barriers via ctr[0..11])
    lstm_fused<<<dim3(16, 12), 256, 0, stream>>>(xz, Wh_s, stmt, ctr);
    // 3) everything else, one persistent kernel (grid barriers via ctr[12])
    mega<<<dim3(MEGA_GRID), 512, 0, stream>>>(stmt, W_se, Wx_e, W_sd, Wh_e, hw, cz, ck,
                                              W_d1, code_length, pref, s_, q, ve, r_, rT,
                                              spT_mid, spT0, spT5, c0, c1, h0, h1,
                                              p0, p1, out, ctr + 12);
}

// Round 2
// 580.160 us; speedup vs baseline: 3.6935x; 3.6935x over previous
//
#include <hip/hip_runtime.h>
#include <cstddef>

// Problem constants
#define B_   4
#define NS_  96
#define T_   8
#define H_   256
#define N_   97      // NS + 1
#define NL_  6       // NUM_LAYERS
#define R_   388     // B_ * N_

// fast gates: v_exp_f32 (2^x) + v_rcp_f32
__device__ __forceinline__ float sigm(float x) {
    return __builtin_amdgcn_rcpf(1.0f + __builtin_amdgcn_exp2f(-1.44269504f * x));
}
__device__ __forceinline__ float tanh_f(float x) {
    return 1.0f - 2.0f * __builtin_amdgcn_rcpf(1.0f + __builtin_amdgcn_exp2f(2.88539008f * x));
}

__device__ __forceinline__ void fma16(float4 a, float4 w0, float4 w1, float4 w2,
                                      float4 w3, float* acc) {
    acc[0] = fmaf(a.x, w0.x, acc[0]); acc[1] = fmaf(a.x, w0.y, acc[1]);
    acc[2] = fmaf(a.x, w0.z, acc[2]); acc[3] = fmaf(a.x, w0.w, acc[3]);
    acc[0] = fmaf(a.y, w1.x, acc[0]); acc[1] = fmaf(a.y, w1.y, acc[1]);
    acc[2] = fmaf(a.y, w1.z, acc[2]); acc[3] = fmaf(a.y, w1.w, acc[3]);
    acc[0] = fmaf(a.z, w2.x, acc[0]); acc[1] = fmaf(a.z, w2.y, acc[1]);
    acc[2] = fmaf(a.z, w2.z, acc[2]); acc[3] = fmaf(a.z, w2.w, acc[3]);
    acc[0] = fmaf(a.w, w3.x, acc[0]); acc[1] = fmaf(a.w, w3.y, acc[1]);
    acc[2] = fmaf(a.w, w3.z, acc[2]); acc[3] = fmaf(a.w, w3.w, acc[3]);
}

// ============ prologue: 512-thr blocks ============
// bid<384: xz 64x128 tiles; 384-385: cz; 386-387: hw; 388: ck + ctr zero; 389..437: init.
__global__ __launch_bounds__(512) void prologue(
        const int* __restrict__ ids, const float* __restrict__ embed,
        const float* __restrict__ Wx_s, const float* __restrict__ b_s,
        const float* __restrict__ b_se, const float* __restrict__ Wx_e,
        const float* __restrict__ b_e, const float* __restrict__ W_sd,
        const float* __restrict__ b_sd, const float* __restrict__ Wh_e,
        const float* __restrict__ init_a, const float* __restrict__ init_b,
        float* __restrict__ xz, float* __restrict__ cz, float* __restrict__ ck,
        float* __restrict__ hw, float* __restrict__ c0, float* __restrict__ h0,
        float* __restrict__ p0, int* __restrict__ ctr) {
    int bid = blockIdx.x, t = threadIdx.x;
    if (bid < 384) {                      // xz = embed[ids] @ Wx_s + b_s, 64x128 tile
        __shared__ float As[64][260];
        __shared__ int ridx[64];
        int r0 = (bid >> 3) * 64, n0 = (bid & 7) * 128;
        if (t < 64) ridx[t] = ids[r0 + t];
        __syncthreads();
#pragma unroll
        for (int m = 0; m < 8; m++) {     // stage 64x256 (8 float4/thread)
            int L = m * 512 + t;
            int r = L >> 6, c4 = (L & 63) * 4;
            *(float4*)&As[r][c4] = *(const float4*)(embed + (size_t)ridx[r] * 256 + c4);
        }
        __syncthreads();
        int rg = t >> 5, cg = t & 31;     // 16 row-groups x 32 col-quads
        float acc[4][4] = {};
        const float* wp = Wx_s + n0 + 4 * cg;
#pragma unroll 4
        for (int kb = 0; kb < 64; kb++) {
            float4 w0 = *(const float4*)(wp + (size_t)(4 * kb + 0) * 1024);
            float4 w1 = *(const float4*)(wp + (size_t)(4 * kb + 1) * 1024);
            float4 w2 = *(const float4*)(wp + (size_t)(4 * kb + 2) * 1024);
            float4 w3 = *(const float4*)(wp + (size_t)(4 * kb + 3) * 1024);
#pragma unroll
            for (int i = 0; i < 4; i++) {
                float4 a = *(const float4*)&As[rg * 4 + i][4 * kb];
                fma16(a, w0, w1, w2, w3, acc[i]);
            }
        }
        int col = n0 + 4 * cg;
        float4 bv = *(const float4*)&b_s[col];
#pragma unroll
        for (int i = 0; i < 4; i++) {
            int r = r0 + rg * 4 + i;
            float4 o = make_float4(acc[i][0] + bv.x, acc[i][1] + bv.y,
                                   acc[i][2] + bv.z, acc[i][3] + bv.w);
            *(float4*)&xz[(size_t)r * 1024 + col] = o;
        }
    } else if (bid < 386) {               // cz[n] = b_e + b_se@Wx_e
        int n = (bid - 384) * 512 + t;
        float acc = b_e[n];
        for (int k = 0; k < 256; k++) acc = fmaf(b_se[k], Wx_e[(size_t)k * 1024 + n], acc);
        cz[n] = acc;
    } else if (bid < 388) {               // hw[n] = cz[n] + init_b@Wh_e
        int n = (bid - 386) * 512 + t;
        float acc = b_e[n];
        for (int k = 0; k < 256; k++) {
            acc = fmaf(b_se[k], Wx_e[(size_t)k * 1024 + n], acc);
            acc = fmaf(init_b[k], Wh_e[(size_t)k * 1024 + n], acc);
        }
        hw[n] = acc;
    } else if (bid == 388) {              // ck + barrier-counter zeroing
        ctr[t] = 0;                       // 512 ints (12 padded lstm group ctrs)
        if (t < 256) {
            float acc = b_sd[t];
            for (int k = 0; k < 256; k++) acc = fmaf(b_se[k], W_sd[(size_t)k * 256 + t], acc);
            ck[t] = acc;
        }
    } else {                              // init c0/h0/p0: 8 rows per block
        int r0 = (bid - 389) * 8 + (t >> 8) * 4;
        int col = t & 255;
        float ia = init_a[col], ib = init_b[col];
#pragma unroll
        for (int rr = 0; rr < 4; rr++) {
            int row = r0 + rr;
            if (row < R_) {
                c0[(size_t)row * 256 + col] = ia;
                h0[(size_t)row * 256 + col] = ib;
                if (col == 0) p0[row] = ((row % N_) == 0) ? 1.0f : 0.0f;
            }
        }
    }
}

// ============ fused LSTM: all 8 steps in one persistent kernel ============
// grid (16 ct, 12 st), 256 thr, 1 block/CU (106KB LDS), 192 blocks co-resident.
// Wh staged ONCE; cell state in 2 registers; h exchanged via per-st group barriers
// (16 blocks per counter; counters padded to separate cachelines).
__global__ __launch_bounds__(256) void lstm_fused(const float* __restrict__ xz,
        const float* __restrict__ Wh, float* __restrict__ hbuf, int* __restrict__ ctr) {
    __shared__ float Wh_s[256][64];
    __shared__ float h_s[32][260];
    __shared__ float zs[32][68];
    int t = threadIdx.x;
    int ct = blockIdx.x, st = blockIdx.y;
    int et0 = ct * 16, s0 = st * 32;
    int* myctr = ctr + st * 32;           // 128B stride: no false sharing
    // stage Wh slice once for all 8 steps
#pragma unroll
    for (int m = 0; m < 16; m++) {
        int L = m * 256 + t;
        int k = L >> 4, f = L & 15;
        int gg = f >> 2, qq = f & 3;
        *(float4*)&Wh_s[k][f * 4] = *(const float4*)&Wh[(size_t)k * 1024 + gg * 256 + et0 + qq * 4];
    }
    // ---- step 0: h0 computed locally for all 32 stmts, all 256 cols ----
    for (int seq = 0; seq < 32; seq++) {
        const float* z0 = xz + ((size_t)(s0 + seq) * T_) * 1024;
        float gi = z0[t], gg = z0[512 + t], go = z0[768 + t];
        float c0v = sigm(gi) * tanh_f(gg);
        h_s[seq][t] = sigm(go) * tanh_f(c0v);
    }
    float creg[2];
    {
        int sqA = t >> 4, e = et0 + (t & 15);
#pragma unroll
        for (int u = 0; u < 2; u++) {
            const float* z0 = xz + ((size_t)(s0 + sqA + u * 16) * T_) * 1024;
            creg[u] = sigm(z0[e]) * tanh_f(z0[512 + e]);
        }
    }
    __syncthreads();
    int sp = t >> 4, cq = t & 15;
    int g = cq >> 2, q4 = cq & 3;
    int gcol = g * 256 + et0 + q4 * 4;
    int seqA = t >> 4, e = t & 15;
    int epoch = 0;
    for (int step = 1; step < T_; step++) {
        if (step >= 2) {                  // re-stage h (written by all 16 ct-blocks)
#pragma unroll
            for (int m = 0; m < 8; m++) {
                int L = m * 256 + t;
                int seq = L >> 6, c4 = (L & 63) * 4;
                *(float4*)&h_s[seq][c4] = *(const float4*)&hbuf[(size_t)(s0 + seq) * H_ + c4];
            }
            __syncthreads();
        }
        float4 a0 = *(const float4*)(xz + ((size_t)(s0 + sp) * T_ + step) * 1024 + gcol);
        float4 a1 = *(const float4*)(xz + ((size_t)(s0 + sp + 16) * T_ + step) * 1024 + gcol);
#pragma unroll 4
        for (int k = 0; k < 256; k++) {
            float4 w4 = *(const float4*)&Wh_s[k][cq * 4];
            float hA = h_s[sp][k];
            float hB = h_s[sp + 16][k];
            a0.x = fmaf(hA, w4.x, a0.x); a0.y = fmaf(hA, w4.y, a0.y);
            a0.z = fmaf(hA, w4.z, a0.z); a0.w = fmaf(hA, w4.w, a0.w);
            a1.x = fmaf(hB, w4.x, a1.x); a1.y = fmaf(hB, w4.y, a1.y);
            a1.z = fmaf(hB, w4.z, a1.z); a1.w = fmaf(hB, w4.w, a1.w);
        }
        *(float4*)&zs[sp][cq * 4] = a0;
        *(float4*)&zs[sp + 16][cq * 4] = a1;
        __syncthreads();
#pragma unroll
        for (int u = 0; u < 2; u++) {
            int seq = seqA + u * 16;
            float gi = zs[seq][e], gf = zs[seq][16 + e], gg = zs[seq][32 + e], go = zs[seq][48 + e];
            float cn = sigm(gf) * creg[u] + sigm(gi) * tanh_f(gg);
            creg[u] = cn;
            hbuf[(size_t)(s0 + seq) * H_ + et0 + e] = sigm(go) * tanh_f(cn);
        }
        if (step < T_ - 1) {              // group barrier: 16 ct-blocks of this st
            __threadfence();
            __syncthreads();
            epoch++;
            if (t == 0) {
                atomicAdd(myctr, 1);
                while (__hip_atomic_load(myctr, __ATOMIC_ACQUIRE,
                                         __HIP_MEMORY_SCOPE_AGENT) < 16 * epoch)
                    __builtin_amdgcn_s_sleep(1);
            }
            __syncthreads();
            __threadfence();
        }
    }
}

// ============ templated GEMM: C = A@W (+bias)(-subQ), p-gated rows, MT x 128 tile ============
template<int MT>
__global__ __launch_bounds__(256) void gemm_t(const float* __restrict__ A,
        const float* __restrict__ W, const float* __restrict__ bias,
        const float* __restrict__ subQ, const float* __restrict__ pgate,
        float* __restrict__ C, int R, int NC) {
    __shared__ float As[MT][260];
    __shared__ int anyflag;
    int t = threadIdx.x;
    int n0 = blockIdx.x * 128;
    int r0 = blockIdx.y * MT;
    if (pgate) {                          // skip blocks whose rows all have p == 0
        if (t == 0) anyflag = 0;
        __syncthreads();
        if (t < MT && r0 + t < R && pgate[r0 + t] != 0.0f) anyflag = 1;
        __syncthreads();
        if (!anyflag) return;
    }
#pragma unroll
    for (int m = 0; m < MT / 4; m++) {
        int L = m * 256 + t;
        int r = L >> 6, c4 = (L & 63) * 4;
        int rr = r0 + r;
        float4 v = make_float4(0.f, 0.f, 0.f, 0.f);
        if (rr < R) v = *(const float4*)(A + (size_t)rr * 256 + c4);
        *(float4*)&As[r][c4] = v;
    }
    __syncthreads();
    constexpr int RT = MT / 8;
    int rg = t >> 5, cg = t & 31;
    float acc[RT][4] = {};
    const float* wp = W + n0 + 4 * cg;
#pragma unroll 2
    for (int kb = 0; kb < 64; kb++) {
        float4 w0 = *(const float4*)(wp + (size_t)(4 * kb + 0) * NC);
        float4 w1 = *(const float4*)(wp + (size_t)(4 * kb + 1) * NC);
        float4 w2 = *(const float4*)(wp + (size_t)(4 * kb + 2) * NC);
        float4 w3 = *(const float4*)(wp + (size_t)(4 * kb + 3) * NC);
#pragma unroll
        for (int i = 0; i < RT; i++) {
            float4 a = *(const float4*)&As[rg * RT + i][4 * kb];
            fma16(a, w0, w1, w2, w3, acc[i]);
        }
    }
    int col = n0 + 4 * cg;
    float4 bv = make_float4(0.f, 0.f, 0.f, 0.f);
    if (bias) bv = *(const float4*)&bias[col];
#pragma unroll
    for (int i = 0; i < RT; i++) {
        int r = r0 + rg * RT + i;
        if (r < R) {
            float4 o = make_float4(acc[i][0] + bv.x, acc[i][1] + bv.y,
                                   acc[i][2] + bv.z, acc[i][3] + bv.w);
            if (subQ) {
                float4 s4 = *(const float4*)(subQ + (size_t)r * NC + col);
                o.x -= s4.x; o.y -= s4.y; o.z -= s4.z; o.w -= s4.w;
            }
            *(float4*)&C[(size_t)r * NC + col] = o;
        }
    }
}

// ============ merged q/r GEMM: bx<8 -> q (and ve0 = hw - q); else r (+rT) ============
__global__ __launch_bounds__(256) void qr_kernel(const float* __restrict__ S,
        const float* __restrict__ Wx_e, const float* __restrict__ W_sd,
        const float* __restrict__ hw, float* __restrict__ q, float* __restrict__ ve0,
        float* __restrict__ r_, float* __restrict__ rT) {
    __shared__ float As[16][260];
    int t = threadIdx.x;
    int bx = blockIdx.x;
    int r0 = blockIdx.y * 16;
#pragma unroll
    for (int m = 0; m < 4; m++) {
        int L = m * 256 + t;
        int r = L >> 6, c4 = (L & 63) * 4;
        int rr = r0 + r;
        float4 v = make_float4(0.f, 0.f, 0.f, 0.f);
        if (rr < R_) v = *(const float4*)(S + (size_t)rr * 256 + c4);
        *(float4*)&As[r][c4] = v;
    }
    __syncthreads();
    bool isq = bx < 8;
    const float* W = isq ? Wx_e : W_sd;
    int NC = isq ? 1024 : 256;
    int n0 = (isq ? bx : bx - 8) * 128;
    int rg = t >> 5, cg = t & 31;
    float acc[2][4] = {};
    const float* wp = W + n0 + 4 * cg;
#pragma unroll 2
    for (int kb = 0; kb < 64; kb++) {
        float4 w0 = *(const float4*)(wp + (size_t)(4 * kb + 0) * NC);
        float4 w1 = *(const float4*)(wp + (size_t)(4 * kb + 1) * NC);
        float4 w2 = *(const float4*)(wp + (size_t)(4 * kb + 2) * NC);
        float4 w3 = *(const float4*)(wp + (size_t)(4 * kb + 3) * NC);
#pragma unroll
        for (int i = 0; i < 2; i++) {
            float4 a = *(const float4*)&As[rg * 2 + i][4 * kb];
            fma16(a, w0, w1, w2, w3, acc[i]);
        }
    }
    int col = n0 + 4 * cg;
#pragma unroll
    for (int i = 0; i < 2; i++) {
        int r = r0 + rg * 2 + i;
        if (r < R_) {
            float4 o = make_float4(acc[i][0], acc[i][1], acc[i][2], acc[i][3]);
            if (isq) {
                *(float4*)&q[(size_t)r * 1024 + col] = o;
                float4 hwv = *(const float4*)&hw[col];   // ve0 = hw - q (h0 rows identical)
                float4 v0 = make_float4(hwv.x - o.x, hwv.y - o.y, hwv.z - o.z, hwv.w - o.w);
                *(float4*)&ve0[(size_t)r * 1024 + col] = v0;
            } else {
                *(float4*)&r_[(size_t)r * 256 + col] = o;
                int b = r / N_, n = r - b * N_;
                rT[((size_t)b * 256 + col + 0) * 128 + n] = o.x;
                rT[((size_t)b * 256 + col + 1) * 128 + n] = o.y;
                rT[((size_t)b * 256 + col + 2) * 128 + n] = o.z;
                rT[((size_t)b * 256 + col + 3) * 128 + n] = o.w;
            }
        }
    }
}

// ============ cumsum: stage whole batch in LDS, scan in-LDS ============
__global__ __launch_bounds__(1024) void cumsum_k(const float* __restrict__ stmt,
                                                 float* __restrict__ pref) {
    __shared__ float buf[96][256];       // 98.3 KB
    int b = blockIdx.x, t = threadIdx.x;
#pragma unroll
    for (int m = 0; m < 6; m++) {        // 6144 float4, coalesced, independent
        int L = m * 1024 + t;
        int r = L >> 6, c4 = (L & 63) * 4;
        *(float4*)&buf[r][c4] = *(const float4*)(stmt + ((size_t)b * NS_ + r) * 256 + c4);
    }
    __syncthreads();
    if (t < 256) {
        float run = 0.0f;
        pref[((size_t)b * N_) * H_ + t] = 0.0f;
        for (int n = 1; n < N_; n++) {
            run += buf[n - 1][t];
            pref[((size_t)b * N_ + n) * H_ + t] = run;
        }
    }
}

// ============ ONCE: logits + masked softmax (layer-invariant) ============
__global__ void softmax_once(const float* __restrict__ r, const float* __restrict__ rT,
                             const float* __restrict__ ck, const float* __restrict__ Wd1,
                             const int* __restrict__ code_length,
                             float* __restrict__ spT_mid, float* __restrict__ spT0,
                             float* __restrict__ spT5) {
    __shared__ float ri[H_], ckl[H_], wd[H_];
    __shared__ float part[8][128];
    __shared__ float red[128];
    int t = threadIdx.x;             // 0..1023
    int j = t & 127, half = t >> 7;
    int bi = blockIdx.x;
    int b = bi / N_, i = bi % N_;
    if (t < H_) {
        ri[t] = r[(size_t)bi * H_ + t];
        ckl[t] = ck[t];
        wd[t] = Wd1[256 + t];
    }
    __syncthreads();
    int len = code_length[b] / T_;
    bool valid = (j < N_) && ((j > i && j <= len) || (j == len));
    float acc = 0.0f;
    if (valid) {
        const float* rTb = rT + (size_t)b * H_ * 128 + j;
        int h0 = half * 32;
#pragma unroll 4
        for (int hh = 0; hh < 32; hh++) {
            int h = h0 + hh;
            float v = rTb[(size_t)h * 128] - ri[h] + ckl[h];
            acc = fmaf(fmaxf(v, 0.0f), wd[h], acc);
        }
    }
    part[half][j] = acc;
    __syncthreads();
    float logit = -3.0e38f;
    if (t < 128) {
        if (valid)
            logit = part[0][j] + part[1][j] + part[2][j] + part[3][j]
                  + part[4][j] + part[5][j] + part[6][j] + part[7][j];
        red[j] = logit;
    }
    __syncthreads();
    for (int off = 64; off; off >>= 1) {
        if (t < off) red[t] = fmaxf(red[t], red[t + off]);
        __syncthreads();
    }
    float m = red[0];
    __syncthreads();
    float e = (t < 128 && valid) ? __builtin_amdgcn_exp2f(1.44269504f * (logit - m)) : 0.0f;
    if (t < 128) red[j] = e;
    __syncthreads();
    for (int off = 64; off; off >>= 1) {
        if (t < off) red[t] += red[t + off];
        __syncthreads();
    }
    float s = red[0];
    if (t < 128 && j < N_) {
        size_t o = ((size_t)b * N_ + j) * 128 + i;
        spT_mid[o] = e / s;
        spT0[o] = (j == 1) ? 1.0f : 0.0f;
        spT5[o] = (j == len) ? 1.0f : 0.0f;
    }
}

// ============ per-layer aggregate: gates = q[j] + ve[i]; 512 thr ============
__global__ __launch_bounds__(512) void aggregate(const float* __restrict__ q,
        const float* __restrict__ ve, const float* __restrict__ spT,
        const float* __restrict__ p, const float* __restrict__ cc,
        const float* __restrict__ hc, float* __restrict__ cn,
        float* __restrict__ hn, float* __restrict__ pn) {
    __shared__ float qj[1024];
    __shared__ float wcol[128];
    __shared__ float red[128];
    __shared__ int vlist[128];
    __shared__ int nv_s;
    __shared__ float parts[2][2][H_];
    int t = threadIdx.x;
    int bj = blockIdx.x;
    int b = bj / N_, j = bj - b * N_;
    if (t < 128) {
        float wv = (t < N_) ? spT[(size_t)bj * 128 + t] * p[b * N_ + t] : 0.f;
        wcol[t] = wv;
        red[t] = wv;
    }
    __syncthreads();
    if (t == 0) {
        int nv = 0;
        for (int i = 0; i < N_; i++)
            if (wcol[i] != 0.0f) vlist[nv++] = i;
        nv_s = nv;
    }
    __syncthreads();
    for (int off = 64; off; off >>= 1) {
        if (t < off) red[t] += red[t + off];
        __syncthreads();
    }
    float wsum = red[0];
    if (wsum == 0.0f) {
        if (t < 256) {
            cn[(size_t)bj * H_ + t] = 0.0f;
            hn[(size_t)bj * H_ + t] = 0.0f;
            if (t == 0) pn[bj] = 0.0f;
        }
        return;
    }
    qj[t] = q[(size_t)bj * 1024 + t];
    qj[512 + t] = q[(size_t)bj * 1024 + 512 + t];
    __syncthreads();
    int hh = t & 255, vs = t >> 8;
    int nv = nv_s;
    float ac = 0.f, ah = 0.f;
    for (int v = vs; v < nv; v += 2) {
        int i = vlist[v];
        float wv = wcol[i];
        size_t rowi = (size_t)b * N_ + i;
        if (j > i) {
            const float* vei = ve + rowi * 1024;
            float gi = qj[hh] + vei[hh];
            float gf = qj[256 + hh] + vei[256 + hh];
            float gg = qj[512 + hh] + vei[512 + hh];
            float go = qj[768 + hh] + vei[768 + hh];
            float c2 = cc[rowi * H_ + hh];
            float cp = sigm(gf) * c2 + sigm(gi) * tanh_f(gg);
            float hp = sigm(go) * tanh_f(cp);
            ac = fmaf(wv, cp, ac);
            ah = fmaf(wv, hp, ah);
        } else {
            ac = fmaf(wv, cc[rowi * H_ + hh], ac);
            ah = fmaf(wv, hc[rowi * H_ + hh], ah);
        }
    }
    parts[vs][0][hh] = ac;
    parts[vs][1][hh] = ah;
    __syncthreads();
    if (t < 256) {
        float inv = __builtin_amdgcn_rcpf(wsum + 1e-7f);
        cn[(size_t)bj * H_ + t] = (parts[0][0][t] + parts[1][0][t]) * inv;
        hn[(size_t)bj * H_ + t] = (parts[0][1][t] + parts[1][1][t]) * inv;
        if (t == 0) pn[bj] = wsum;
    }
}

// ---------------- host launcher ----------------

extern "C" void kernel_launch(void* const* d_in, const int* in_sizes, int n_in,
                              void* d_out, int out_size, void* d_ws, size_t ws_size,
                              hipStream_t stream) {
    const int*   code_statements = (const int*)d_in[0];
    const int*   code_length = (const int*)d_in[1];
    const float* embed = (const float*)d_in[2];
    const float* Wx_s = (const float*)d_in[3];
    const float* Wh_s = (const float*)d_in[4];
    const float* b_s  = (const float*)d_in[5];
    const float* W_se = (const float*)d_in[6];
    const float* b_se = (const float*)d_in[7];
    const float* Wx_e = (const float*)d_in[8];
    const float* Wh_e = (const float*)d_in[9];
    const float* b_e  = (const float*)d_in[10];
    const float* W_sd = (const float*)d_in[13];
    const float* b_sd = (const float*)d_in[14];
    const float* W_d1 = (const float*)d_in[15];
    // d_in[11] W_hk, d_in[12] b_hk, d_in[16] b_d1: softmax-invariant -> unused
    const float* init_a = (const float*)d_in[17];
    const float* init_b = (const float*)d_in[18];
    float* out = (float*)d_out;

    float* wsf = (float*)d_ws;
    size_t off = 0;
    auto alloc = [&](size_t n) { float* p = wsf + off; off += n; return p; };
    float* cz = alloc(1024);
    float* ck = alloc(256);
    float* hw = alloc(1024);             // init_b@Wh_e + cz
    float* xz = alloc((size_t)3072 * 1024);
    float* stmt = alloc(384 * 256);      // LSTM h buffer
    float* pref = alloc(R_ * 256);
    float* s_   = alloc(R_ * 256);       // pref @ W_se
    float* q  = alloc(R_ * 1024);
    float* r_ = alloc(R_ * 256);
    float* rT = alloc(4 * 256 * 128);
    float* ve = alloc(R_ * 1024);        // h@Wh_e + cz - q
    float* spT_mid = alloc(R_ * 128);
    float* spT0    = alloc(R_ * 128);
    float* spT5    = alloc(R_ * 128);
    float* p0 = alloc(R_);
    float* p1 = alloc(R_);
    float* c0 = alloc(R_ * 256);
    float* c1 = alloc(R_ * 256);
    float* h0 = alloc(R_ * 256);
    float* h1 = alloc(R_ * 256);
    int*   ctr = (int*)alloc(512);       // 12 lstm st-group ctrs, 32-int stride

    // 1) prologue: xz tiles + cz/ck/hw + state init + ctr zeroing
    prologue<<<dim3(438), 512, 0, stream>>>(code_statements, embed, Wx_s, b_s,
                                            b_se, Wx_e, b_e, W_sd, b_sd, Wh_e,
                                            init_a, init_b, xz, cz, ck, hw, c0, h0, p0,
                                            ctr);
    // 2) all 8 LSTM steps, one persistent kernel (16-block group barriers)
    lstm_fused<<<dim3(16, 12), 256, 0, stream>>>(xz, Wh_s, stmt, ctr);
    // 3) skip encoder + softmax
    cumsum_k<<<dim3(4), 1024, 0, stream>>>(stmt, pref);
    gemm_t<16><<<dim3(2, 25), 256, 0, stream>>>(pref, W_se, nullptr, nullptr, nullptr,
                                                s_, R_, 256);
    qr_kernel<<<dim3(10, 25), 256, 0, stream>>>(s_, Wx_e, W_sd, hw, q, ve, r_, rT);
    softmax_once<<<dim3(R_), 1024, 0, stream>>>(r_, rT, ck, W_d1, code_length,
                                                spT_mid, spT0, spT5);

    // 4) execution layers (ve0 already produced by qr_kernel)
    for (int layer = 0; layer < NL_; layer++) {
        bool odd = (layer & 1);
        float* pc = odd ? p1 : p0;
        float* pn = odd ? p0 : p1;
        float* cc = odd ? c1 : c0;
        float* cn = odd ? c0 : c1;
        float* hc = odd ? h1 : h0;
        float* hn = odd ? h0 : h1;
        if (layer == NL_ - 1) hn = out;  // final h straight to d_out
        const float* spT = (layer == 0) ? spT0 : (layer == NL_ - 1) ? spT5 : spT_mid;
        aggregate<<<dim3(R_), 512, 0, stream>>>(q, ve, spT, pc, cc, hc, cn, hn, pn);
        if (layer < NL_ - 1)
            gemm_t<16><<<dim3(8, 25), 256, 0, stream>>>(hn, Wh_e, cz, q, pn,
                                                        ve, R_, 1024);
    }
}

// Round 3
// 382.121 us; speedup vs baseline: 5.6077x; 1.5183x over previous
//
#include <hip/hip_runtime.h>
#include <cstddef>

// Problem constants
#define B_   4
#define NS_  96
#define T_   8
#define H_   256
#define N_   97      // NS + 1
#define NL_  6       // NUM_LAYERS
#define R_   388     // B_ * N_

// fast gates: v_exp_f32 (2^x) + v_rcp_f32
__device__ __forceinline__ float sigm(float x) {
    return __builtin_amdgcn_rcpf(1.0f + __builtin_amdgcn_exp2f(-1.44269504f * x));
}
__device__ __forceinline__ float tanh_f(float x) {
    return 1.0f - 2.0f * __builtin_amdgcn_rcpf(1.0f + __builtin_amdgcn_exp2f(2.88539008f * x));
}

__device__ __forceinline__ void fma16(float4 a, float4 w0, float4 w1, float4 w2,
                                      float4 w3, float* acc) {
    acc[0] = fmaf(a.x, w0.x, acc[0]); acc[1] = fmaf(a.x, w0.y, acc[1]);
    acc[2] = fmaf(a.x, w0.z, acc[2]); acc[3] = fmaf(a.x, w0.w, acc[3]);
    acc[0] = fmaf(a.y, w1.x, acc[0]); acc[1] = fmaf(a.y, w1.y, acc[1]);
    acc[2] = fmaf(a.y, w1.z, acc[2]); acc[3] = fmaf(a.y, w1.w, acc[3]);
    acc[0] = fmaf(a.z, w2.x, acc[0]); acc[1] = fmaf(a.z, w2.y, acc[1]);
    acc[2] = fmaf(a.z, w2.z, acc[2]); acc[3] = fmaf(a.z, w2.w, acc[3]);
    acc[0] = fmaf(a.w, w3.x, acc[0]); acc[1] = fmaf(a.w, w3.y, acc[1]);
    acc[2] = fmaf(a.w, w3.z, acc[2]); acc[3] = fmaf(a.w, w3.w, acc[3]);
}

// ============ prologue: 512-thr blocks, unroll-4 W-load pipeline ============
// bid<384: xz 64x128 tiles; 384-385: cz; 386-387: hw; 388: ck; 389..437: init.
__global__ __launch_bounds__(512) void prologue(
        const int* __restrict__ ids, const float* __restrict__ embed,
        const float* __restrict__ Wx_s, const float* __restrict__ b_s,
        const float* __restrict__ b_se, const float* __restrict__ Wx_e,
        const float* __restrict__ b_e, const float* __restrict__ W_sd,
        const float* __restrict__ b_sd, const float* __restrict__ Wh_e,
        const float* __restrict__ init_a, const float* __restrict__ init_b,
        float* __restrict__ xz, float* __restrict__ cz, float* __restrict__ ck,
        float* __restrict__ hw, float* __restrict__ c0, float* __restrict__ h0,
        float* __restrict__ p0) {
    int bid = blockIdx.x, t = threadIdx.x;
    if (bid < 384) {                      // xz = embed[ids] @ Wx_s + b_s, 64x128 tile
        __shared__ float As[64][260];
        __shared__ int ridx[64];
        int r0 = (bid >> 3) * 64, n0 = (bid & 7) * 128;
        if (t < 64) ridx[t] = ids[r0 + t];
        __syncthreads();
#pragma unroll
        for (int m = 0; m < 8; m++) {     // stage 64x256 (8 float4/thread)
            int L = m * 512 + t;
            int r = L >> 6, c4 = (L & 63) * 4;
            *(float4*)&As[r][c4] = *(const float4*)(embed + (size_t)ridx[r] * 256 + c4);
        }
        __syncthreads();
        int rg = t >> 5, cg = t & 31;     // 16 row-groups x 32 col-quads
        float acc[4][4] = {};
        const float* wp = Wx_s + n0 + 4 * cg;
#pragma unroll 4
        for (int kb = 0; kb < 64; kb++) {
            float4 w0 = *(const float4*)(wp + (size_t)(4 * kb + 0) * 1024);
            float4 w1 = *(const float4*)(wp + (size_t)(4 * kb + 1) * 1024);
            float4 w2 = *(const float4*)(wp + (size_t)(4 * kb + 2) * 1024);
            float4 w3 = *(const float4*)(wp + (size_t)(4 * kb + 3) * 1024);
#pragma unroll
            for (int i = 0; i < 4; i++) {
                float4 a = *(const float4*)&As[rg * 4 + i][4 * kb];
                fma16(a, w0, w1, w2, w3, acc[i]);
            }
        }
        int col = n0 + 4 * cg;
        float4 bv = *(const float4*)&b_s[col];
#pragma unroll
        for (int i = 0; i < 4; i++) {
            int r = r0 + rg * 4 + i;
            float4 o = make_float4(acc[i][0] + bv.x, acc[i][1] + bv.y,
                                   acc[i][2] + bv.z, acc[i][3] + bv.w);
            *(float4*)&xz[(size_t)r * 1024 + col] = o;
        }
    } else if (bid < 386) {               // cz[n] = b_e + b_se@Wx_e
        int n = (bid - 384) * 512 + t;
        float acc = b_e[n];
        for (int k = 0; k < 256; k++) acc = fmaf(b_se[k], Wx_e[(size_t)k * 1024 + n], acc);
        cz[n] = acc;
    } else if (bid < 388) {               // hw[n] = cz[n] + init_b@Wh_e
        int n = (bid - 386) * 512 + t;
        float acc = b_e[n];
        for (int k = 0; k < 256; k++) {
            acc = fmaf(b_se[k], Wx_e[(size_t)k * 1024 + n], acc);
            acc = fmaf(init_b[k], Wh_e[(size_t)k * 1024 + n], acc);
        }
        hw[n] = acc;
    } else if (bid == 388) {              // ck
        if (t < 256) {
            float acc = b_sd[t];
            for (int k = 0; k < 256; k++) acc = fmaf(b_se[k], W_sd[(size_t)k * 256 + t], acc);
            ck[t] = acc;
        }
    } else {                              // init c0/h0/p0: 8 rows per block
        int r0 = (bid - 389) * 8 + (t >> 8) * 4;
        int col = t & 255;
        float ia = init_a[col], ib = init_b[col];
#pragma unroll
        for (int rr = 0; rr < 4; rr++) {
            int row = r0 + rr;
            if (row < R_) {
                c0[(size_t)row * 256 + col] = ia;
                h0[(size_t)row * 256 + col] = ib;
                if (col == 0) p0[row] = ((row % N_) == 0) ? 1.0f : 0.0f;
            }
        }
    }
}

// ============ LSTM steps 0+1 fused ============
__global__ __launch_bounds__(256) void lstm_first(const float* __restrict__ xz,
        const float* __restrict__ Wh, float* __restrict__ hbuf, float* __restrict__ cbuf) {
    __shared__ float Wh_s[256][64];
    __shared__ float h_s[32][260];
    __shared__ float zs[32][68];
    int t = threadIdx.x;
    int ct = blockIdx.x, st = blockIdx.y;
    int et0 = ct * 16, s0 = st * 32;
#pragma unroll
    for (int m = 0; m < 16; m++) {
        int L = m * 256 + t;
        int k = L >> 4, f = L & 15;
        int gg = f >> 2, qq = f & 3;
        *(float4*)&Wh_s[k][f * 4] = *(const float4*)&Wh[(size_t)k * 1024 + gg * 256 + et0 + qq * 4];
    }
    for (int seq = 0; seq < 32; seq++) {
        const float* z0 = xz + ((size_t)(s0 + seq) * T_) * 1024;
        float gi = z0[t], gg = z0[512 + t], go = z0[768 + t];
        float c0v = sigm(gi) * tanh_f(gg);
        h_s[seq][t] = sigm(go) * tanh_f(c0v);
    }
    float creg[2];
    {
        int sqA = t >> 4, e = et0 + (t & 15);
#pragma unroll
        for (int u = 0; u < 2; u++) {
            const float* z0 = xz + ((size_t)(s0 + sqA + u * 16) * T_) * 1024;
            creg[u] = sigm(z0[e]) * tanh_f(z0[512 + e]);
        }
    }
    __syncthreads();
    {
        int sp = (t >> 4) & 15, cq = t & 15;
        int g = cq >> 2, q4 = cq & 3;
        int gcol = g * 256 + et0 + q4 * 4;
        float4 a0 = *(const float4*)(xz + ((size_t)(s0 + sp) * T_ + 1) * 1024 + gcol);
        float4 a1 = *(const float4*)(xz + ((size_t)(s0 + sp + 16) * T_ + 1) * 1024 + gcol);
#pragma unroll 4
        for (int k = 0; k < 256; k++) {
            float4 w4 = *(const float4*)&Wh_s[k][cq * 4];
            float hA = h_s[sp][k];
            float hB = h_s[sp + 16][k];
            a0.x = fmaf(hA, w4.x, a0.x); a0.y = fmaf(hA, w4.y, a0.y);
            a0.z = fmaf(hA, w4.z, a0.z); a0.w = fmaf(hA, w4.w, a0.w);
            a1.x = fmaf(hB, w4.x, a1.x); a1.y = fmaf(hB, w4.y, a1.y);
            a1.z = fmaf(hB, w4.z, a1.z); a1.w = fmaf(hB, w4.w, a1.w);
        }
        *(float4*)&zs[sp][cq * 4] = a0;
        *(float4*)&zs[sp + 16][cq * 4] = a1;
    }
    __syncthreads();
    {
        int sqA = t >> 4, e = t & 15;
#pragma unroll
        for (int u = 0; u < 2; u++) {
            int seq = sqA + u * 16;
            float gi = zs[seq][e], gf = zs[seq][16 + e], gg = zs[seq][32 + e], go = zs[seq][48 + e];
            float cn = sigm(gf) * creg[u] + sigm(gi) * tanh_f(gg);
            size_t gidx = (size_t)(s0 + seq) * H_ + et0 + e;
            cbuf[gidx] = cn;
            hbuf[gidx] = sigm(go) * tanh_f(cn);
        }
    }
}

// ============ LSTM one step (steps 2..7) ============
__global__ __launch_bounds__(256) void lstm_step(int step, const float* __restrict__ xz,
        const float* __restrict__ Wh, float* __restrict__ hbuf, float* __restrict__ cbuf) {
    __shared__ float Wh_s[256][64];
    __shared__ float h_s[32][260];
    __shared__ float zs[32][68];
    int t = threadIdx.x;
    int ct = blockIdx.x, st = blockIdx.y;
    int et0 = ct * 16, s0 = st * 32;
    int sp = t >> 4, cq = t & 15;
    int g = cq >> 2, q4 = cq & 3;
    int gcol = g * 256 + et0 + q4 * 4;
    float4 a0 = *(const float4*)(xz + ((size_t)(s0 + sp) * T_ + step) * 1024 + gcol);
    float4 a1 = *(const float4*)(xz + ((size_t)(s0 + sp + 16) * T_ + step) * 1024 + gcol);
#pragma unroll
    for (int m = 0; m < 16; m++) {
        int L = m * 256 + t;
        int k = L >> 4, f = L & 15;
        int gg = f >> 2, qq = f & 3;
        *(float4*)&Wh_s[k][f * 4] = *(const float4*)&Wh[(size_t)k * 1024 + gg * 256 + et0 + qq * 4];
    }
#pragma unroll
    for (int m = 0; m < 8; m++) {
        int L = m * 256 + t;
        int seq = L >> 6, c4 = (L & 63) * 4;
        *(float4*)&h_s[seq][c4] = *(const float4*)&hbuf[(size_t)(s0 + seq) * H_ + c4];
    }
    __syncthreads();
#pragma unroll 4
    for (int k = 0; k < 256; k++) {
        float4 w4 = *(const float4*)&Wh_s[k][cq * 4];
        float h0 = h_s[sp][k];
        float h1 = h_s[sp + 16][k];
        a0.x = fmaf(h0, w4.x, a0.x); a0.y = fmaf(h0, w4.y, a0.y);
        a0.z = fmaf(h0, w4.z, a0.z); a0.w = fmaf(h0, w4.w, a0.w);
        a1.x = fmaf(h1, w4.x, a1.x); a1.y = fmaf(h1, w4.y, a1.y);
        a1.z = fmaf(h1, w4.z, a1.z); a1.w = fmaf(h1, w4.w, a1.w);
    }
    *(float4*)&zs[sp][cq * 4] = a0;
    *(float4*)&zs[sp + 16][cq * 4] = a1;
    __syncthreads();
    int seqA = t >> 4, e = t & 15;
#pragma unroll
    for (int u = 0; u < 2; u++) {
        int seq = seqA + u * 16;
        float gi = zs[seq][e], gf = zs[seq][16 + e], gg = zs[seq][32 + e], go = zs[seq][48 + e];
        size_t gidx = (size_t)(s0 + seq) * H_ + et0 + e;
        float cnew = sigm(gf) * cbuf[gidx] + sigm(gi) * tanh_f(gg);
        cbuf[gidx] = cnew;
        hbuf[gidx] = sigm(go) * tanh_f(cnew);
    }
}

// ============ templated GEMM: C = A@W (+bias)(-subQ), p-gated rows, MT x 128 tile ============
template<int MT>
__global__ __launch_bounds__(256) void gemm_t(const float* __restrict__ A,
        const float* __restrict__ W, const float* __restrict__ bias,
        const float* __restrict__ subQ, const float* __restrict__ pgate,
        float* __restrict__ C, int R, int NC) {
    __shared__ float As[MT][260];
    __shared__ int anyflag;
    int t = threadIdx.x;
    int n0 = blockIdx.x * 128;
    int r0 = blockIdx.y * MT;
    if (pgate) {                          // skip blocks whose rows all have p == 0
        if (t == 0) anyflag = 0;
        __syncthreads();
        if (t < MT && r0 + t < R && pgate[r0 + t] != 0.0f) anyflag = 1;
        __syncthreads();
        if (!anyflag) return;
    }
#pragma unroll
    for (int m = 0; m < MT / 4; m++) {
        int L = m * 256 + t;
        int r = L >> 6, c4 = (L & 63) * 4;
        int rr = r0 + r;
        float4 v = make_float4(0.f, 0.f, 0.f, 0.f);
        if (rr < R) v = *(const float4*)(A + (size_t)rr * 256 + c4);
        *(float4*)&As[r][c4] = v;
    }
    __syncthreads();
    constexpr int RT = MT / 8;
    int rg = t >> 5, cg = t & 31;
    float acc[RT][4] = {};
    const float* wp = W + n0 + 4 * cg;
#pragma unroll 2
    for (int kb = 0; kb < 64; kb++) {
        float4 w0 = *(const float4*)(wp + (size_t)(4 * kb + 0) * NC);
        float4 w1 = *(const float4*)(wp + (size_t)(4 * kb + 1) * NC);
        float4 w2 = *(const float4*)(wp + (size_t)(4 * kb + 2) * NC);
        float4 w3 = *(const float4*)(wp + (size_t)(4 * kb + 3) * NC);
#pragma unroll
        for (int i = 0; i < RT; i++) {
            float4 a = *(const float4*)&As[rg * RT + i][4 * kb];
            fma16(a, w0, w1, w2, w3, acc[i]);
        }
    }
    int col = n0 + 4 * cg;
    float4 bv = make_float4(0.f, 0.f, 0.f, 0.f);
    if (bias) bv = *(const float4*)&bias[col];
#pragma unroll
    for (int i = 0; i < RT; i++) {
        int r = r0 + rg * RT + i;
        if (r < R) {
            float4 o = make_float4(acc[i][0] + bv.x, acc[i][1] + bv.y,
                                   acc[i][2] + bv.z, acc[i][3] + bv.w);
            if (subQ) {
                float4 s4 = *(const float4*)(subQ + (size_t)r * NC + col);
                o.x -= s4.x; o.y -= s4.y; o.z -= s4.z; o.w -= s4.w;
            }
            *(float4*)&C[(size_t)r * NC + col] = o;
        }
    }
}

// ============ merged q/r GEMM: bx<8 -> q (and ve0 = hw - q); else r (+rT) ============
__global__ __launch_bounds__(256) void qr_kernel(const float* __restrict__ S,
        const float* __restrict__ Wx_e, const float* __restrict__ W_sd,
        const float* __restrict__ hw, float* __restrict__ q, float* __restrict__ ve0,
        float* __restrict__ r_, float* __restrict__ rT) {
    __shared__ float As[16][260];
    int t = threadIdx.x;
    int bx = blockIdx.x;
    int r0 = blockIdx.y * 16;
#pragma unroll
    for (int m = 0; m < 4; m++) {
        int L = m * 256 + t;
        int r = L >> 6, c4 = (L & 63) * 4;
        int rr = r0 + r;
        float4 v = make_float4(0.f, 0.f, 0.f, 0.f);
        if (rr < R_) v = *(const float4*)(S + (size_t)rr * 256 + c4);
        *(float4*)&As[r][c4] = v;
    }
    __syncthreads();
    bool isq = bx < 8;
    const float* W = isq ? Wx_e : W_sd;
    int NC = isq ? 1024 : 256;
    int n0 = (isq ? bx : bx - 8) * 128;
    int rg = t >> 5, cg = t & 31;
    float acc[2][4] = {};
    const float* wp = W + n0 + 4 * cg;
#pragma unroll 2
    for (int kb = 0; kb < 64; kb++) {
        float4 w0 = *(const float4*)(wp + (size_t)(4 * kb + 0) * NC);
        float4 w1 = *(const float4*)(wp + (size_t)(4 * kb + 1) * NC);
        float4 w2 = *(const float4*)(wp + (size_t)(4 * kb + 2) * NC);
        float4 w3 = *(const float4*)(wp + (size_t)(4 * kb + 3) * NC);
#pragma unroll
        for (int i = 0; i < 2; i++) {
            float4 a = *(const float4*)&As[rg * 2 + i][4 * kb];
            fma16(a, w0, w1, w2, w3, acc[i]);
        }
    }
    int col = n0 + 4 * cg;
#pragma unroll
    for (int i = 0; i < 2; i++) {
        int r = r0 + rg * 2 + i;
        if (r < R_) {
            float4 o = make_float4(acc[i][0], acc[i][1], acc[i][2], acc[i][3]);
            if (isq) {
                *(float4*)&q[(size_t)r * 1024 + col] = o;
                float4 hwv = *(const float4*)&hw[col];   // ve0 = hw - q (h0 rows identical)
                float4 v0 = make_float4(hwv.x - o.x, hwv.y - o.y, hwv.z - o.z, hwv.w - o.w);
                *(float4*)&ve0[(size_t)r * 1024 + col] = v0;
            } else {
                *(float4*)&r_[(size_t)r * 256 + col] = o;
                int b = r / N_, n = r - b * N_;
                rT[((size_t)b * 256 + col + 0) * 128 + n] = o.x;
                rT[((size_t)b * 256 + col + 1) * 128 + n] = o.y;
                rT[((size_t)b * 256 + col + 2) * 128 + n] = o.z;
                rT[((size_t)b * 256 + col + 3) * 128 + n] = o.w;
            }
        }
    }
}

// ============ cumsum: stage whole batch in LDS, scan in-LDS ============
__global__ __launch_bounds__(1024) void cumsum_k(const float* __restrict__ stmt,
                                                 float* __restrict__ pref) {
    __shared__ float buf[96][256];       // 98.3 KB
    int b = blockIdx.x, t = threadIdx.x;
#pragma unroll
    for (int m = 0; m < 6; m++) {        // 6144 float4, coalesced, independent
        int L = m * 1024 + t;
        int r = L >> 6, c4 = (L & 63) * 4;
        *(float4*)&buf[r][c4] = *(const float4*)(stmt + ((size_t)b * NS_ + r) * 256 + c4);
    }
    __syncthreads();
    if (t < 256) {
        float run = 0.0f;
        pref[((size_t)b * N_) * H_ + t] = 0.0f;
        for (int n = 1; n < N_; n++) {
            run += buf[n - 1][t];
            pref[((size_t)b * N_ + n) * H_ + t] = run;
        }
    }
}

// ============ ONCE: logits + masked softmax (layer-invariant), shuffle reductions ============
__global__ void softmax_once(const float* __restrict__ r, const float* __restrict__ rT,
                             const float* __restrict__ ck, const float* __restrict__ Wd1,
                             const int* __restrict__ code_length,
                             float* __restrict__ spT_mid, float* __restrict__ spT0,
                             float* __restrict__ spT5) {
    __shared__ float ri[H_], ckl[H_], wd[H_];
    __shared__ float part[8][128];
    __shared__ float red[4];
    int t = threadIdx.x;             // 0..1023
    int j = t & 127, half = t >> 7;
    int bi = blockIdx.x;
    int b = bi / N_, i = bi % N_;
    if (t < H_) {
        ri[t] = r[(size_t)bi * H_ + t];
        ckl[t] = ck[t];
        wd[t] = Wd1[256 + t];
    }
    __syncthreads();
    int len = code_length[b] / T_;
    bool valid = (j < N_) && ((j > i && j <= len) || (j == len));
    float acc = 0.0f;
    if (valid) {
        const float* rTb = rT + (size_t)b * H_ * 128 + j;
        int h0 = half * 32;
#pragma unroll 4
        for (int hh = 0; hh < 32; hh++) {
            int h = h0 + hh;
            float v = rTb[(size_t)h * 128] - ri[h] + ckl[h];
            acc = fmaf(fmaxf(v, 0.0f), wd[h], acc);
        }
    }
    part[half][j] = acc;
    __syncthreads();
    float logit = -3.0e38f;
    if (t < 128) {                   // waves 0,1 fully active
        if (valid)
            logit = part[0][j] + part[1][j] + part[2][j] + part[3][j]
                  + part[4][j] + part[5][j] + part[6][j] + part[7][j];
        float m = logit;
#pragma unroll
        for (int off = 32; off; off >>= 1) m = fmaxf(m, __shfl_xor(m, off));
        if ((t & 63) == 0) red[t >> 6] = m;
    }
    __syncthreads();
    float e = 0.0f;
    if (t < 128) {
        float m = fmaxf(red[0], red[1]);
        e = valid ? __builtin_amdgcn_exp2f(1.44269504f * (logit - m)) : 0.0f;
        float s = e;
#pragma unroll
        for (int off = 32; off; off >>= 1) s += __shfl_xor(s, off);
        if ((t & 63) == 0) red[2 + (t >> 6)] = s;
    }
    __syncthreads();
    if (t < 128 && j < N_) {
        float s = red[2] + red[3];
        size_t o = ((size_t)b * N_ + j) * 128 + i;
        spT_mid[o] = e / s;
        spT0[o] = (j == 1) ? 1.0f : 0.0f;
        spT5[o] = (j == len) ? 1.0f : 0.0f;
    }
}

// ============ per-layer aggregate: ballot compaction + shuffle reductions ============
__global__ __launch_bounds__(512) void aggregate(const float* __restrict__ q,
        const float* __restrict__ ve, const float* __restrict__ spT,
        const float* __restrict__ p, const float* __restrict__ cc,
        const float* __restrict__ hc, float* __restrict__ cn,
        float* __restrict__ hn, float* __restrict__ pn) {
    __shared__ float qj[1024];
    __shared__ float wcol[128];
    __shared__ int vlist[128];
    __shared__ int cnts[2];
    __shared__ float wsums[2];
    __shared__ float parts[2][2][H_];
    int t = threadIdx.x;
    int bj = blockIdx.x;
    int b = bj / N_, j = bj - b * N_;
    bool pred = false;
    int rank = 0;
    if (t < 128) {                   // waves 0,1 fully active
        float wv = (t < N_) ? spT[(size_t)bj * 128 + t] * p[b * N_ + t] : 0.f;
        wcol[t] = wv;
        float s = wv;
#pragma unroll
        for (int off = 32; off; off >>= 1) s += __shfl_xor(s, off);
        pred = (wv != 0.0f);
        unsigned long long mask = __ballot(pred);
        int lane = t & 63;
        rank = __popcll(mask & ((1ull << lane) - 1ull));
        if (lane == 0) { cnts[t >> 6] = (int)__popcll(mask); wsums[t >> 6] = s; }
    }
    __syncthreads();
    float wsum = wsums[0] + wsums[1];
    int nv = cnts[0] + cnts[1];
    if (t < 128 && pred) vlist[(t >= 64 ? cnts[0] : 0) + rank] = t;
    if (wsum == 0.0f) {
        if (t < 256) {
            cn[(size_t)bj * H_ + t] = 0.0f;
            hn[(size_t)bj * H_ + t] = 0.0f;
            if (t == 0) pn[bj] = 0.0f;
        }
        return;
    }
    qj[t] = q[(size_t)bj * 1024 + t];
    qj[512 + t] = q[(size_t)bj * 1024 + 512 + t];
    __syncthreads();                 // covers vlist writes and qj stage
    int hh = t & 255, vs = t >> 8;
    float ac = 0.f, ah = 0.f;
    for (int v = vs; v < nv; v += 2) {
        int i = vlist[v];
        float wv = wcol[i];
        size_t rowi = (size_t)b * N_ + i;
        if (j > i) {
            const float* vei = ve + rowi * 1024;
            float gi = qj[hh] + vei[hh];
            float gf = qj[256 + hh] + vei[256 + hh];
            float gg = qj[512 + hh] + vei[512 + hh];
            float go = qj[768 + hh] + vei[768 + hh];
            float c2 = cc[rowi * H_ + hh];
            float cp = sigm(gf) * c2 + sigm(gi) * tanh_f(gg);
            float hp = sigm(go) * tanh_f(cp);
            ac = fmaf(wv, cp, ac);
            ah = fmaf(wv, hp, ah);
        } else {
            ac = fmaf(wv, cc[rowi * H_ + hh], ac);
            ah = fmaf(wv, hc[rowi * H_ + hh], ah);
        }
    }
    parts[vs][0][hh] = ac;
    parts[vs][1][hh] = ah;
    __syncthreads();
    if (t < 256) {
        float inv = __builtin_amdgcn_rcpf(wsum + 1e-7f);
        cn[(size_t)bj * H_ + t] = (parts[0][0][t] + parts[1][0][t]) * inv;
        hn[(size_t)bj * H_ + t] = (parts[0][1][t] + parts[1][1][t]) * inv;
        if (t == 0) pn[bj] = wsum;
    }
}

// ---------------- host launcher ----------------

extern "C" void kernel_launch(void* const* d_in, const int* in_sizes, int n_in,
                              void* d_out, int out_size, void* d_ws, size_t ws_size,
                              hipStream_t stream) {
    const int*   code_statements = (const int*)d_in[0];
    const int*   code_length = (const int*)d_in[1];
    const float* embed = (const float*)d_in[2];
    const float* Wx_s = (const float*)d_in[3];
    const float* Wh_s = (const float*)d_in[4];
    const float* b_s  = (const float*)d_in[5];
    const float* W_se = (const float*)d_in[6];
    const float* b_se = (const float*)d_in[7];
    const float* Wx_e = (const float*)d_in[8];
    const float* Wh_e = (const float*)d_in[9];
    const float* b_e  = (const float*)d_in[10];
    const float* W_sd = (const float*)d_in[13];
    const float* b_sd = (const float*)d_in[14];
    const float* W_d1 = (const float*)d_in[15];
    // d_in[11] W_hk, d_in[12] b_hk, d_in[16] b_d1: softmax-invariant -> unused
    const float* init_a = (const float*)d_in[17];
    const float* init_b = (const float*)d_in[18];
    float* out = (float*)d_out;

    float* wsf = (float*)d_ws;
    size_t off = 0;
    auto alloc = [&](size_t n) { float* p = wsf + off; off += n; return p; };
    float* cz = alloc(1024);
    float* ck = alloc(256);
    float* hw = alloc(1024);             // init_b@Wh_e + cz
    float* xz = alloc((size_t)3072 * 1024);
    float* stmt = alloc(384 * 256);      // LSTM h buffer
    float* cls = alloc(384 * 256);       // LSTM cell state
    float* pref = alloc(R_ * 256);
    float* s_   = alloc(R_ * 256);       // pref @ W_se
    float* q  = alloc(R_ * 1024);
    float* r_ = alloc(R_ * 256);
    float* rT = alloc(4 * 256 * 128);
    float* ve = alloc(R_ * 1024);        // h@Wh_e + cz - q
    float* spT_mid = alloc(R_ * 128);
    float* spT0    = alloc(R_ * 128);
    float* spT5    = alloc(R_ * 128);
    float* p0 = alloc(R_);
    float* p1 = alloc(R_);
    float* c0 = alloc(R_ * 256);
    float* c1 = alloc(R_ * 256);
    float* h0 = alloc(R_ * 256);
    float* h1 = alloc(R_ * 256);

    // one prologue launch: xz (64x128 tiles) + cz/ck/hw + state init
    prologue<<<dim3(438), 512, 0, stream>>>(code_statements, embed, Wx_s, b_s,
                                            b_se, Wx_e, b_e, W_sd, b_sd, Wh_e,
                                            init_a, init_b, xz, cz, ck, hw, c0, h0, p0);
    // LSTM: steps 0+1 fused, then 2..7 (per-step launches: HW inter-dispatch sync)
    lstm_first<<<dim3(16, 12), 256, 0, stream>>>(xz, Wh_s, stmt, cls);
    for (int step = 2; step < T_; step++)
        lstm_step<<<dim3(16, 12), 256, 0, stream>>>(step, xz, Wh_s, stmt, cls);
    cumsum_k<<<dim3(4), 1024, 0, stream>>>(stmt, pref);
    gemm_t<16><<<dim3(2, 25), 256, 0, stream>>>(pref, W_se, nullptr, nullptr, nullptr,
                                                s_, R_, 256);
    qr_kernel<<<dim3(10, 25), 256, 0, stream>>>(s_, Wx_e, W_sd, hw, q, ve, r_, rT);
    softmax_once<<<dim3(R_), 1024, 0, stream>>>(r_, rT, ck, W_d1, code_length,
                                                spT_mid, spT0, spT5);

    // execution layers (ve0 already produced by qr_kernel)
    for (int layer = 0; layer < NL_; layer++) {
        bool odd = (layer & 1);
        float* pc = odd ? p1 : p0;
        float* pn = odd ? p0 : p1;
        float* cc = odd ? c1 : c0;
        float* cn = odd ? c0 : c1;
        float* hc = odd ? h1 : h0;
        float* hn = odd ? h0 : h1;
        if (layer == NL_ - 1) hn = out;  // final h straight to d_out
        const float* spT = (layer == 0) ? spT0 : (layer == NL_ - 1) ? spT5 : spT_mid;
        aggregate<<<dim3(R_), 512, 0, stream>>>(q, ve, spT, pc, cc, hc, cn, hn, pn);
        if (layer < NL_ - 1)
            gemm_t<16><<<dim3(8, 25), 256, 0, stream>>>(hn, Wh_e, cz, q, pn,
                                                        ve, R_, 1024);
    }
}